// Round 5
// baseline (809.813 us; speedup 1.0000x reference)
//
#include <hip/hip_runtime.h>
#include <hip/hip_bf16.h>

// Tanh-RNN: B=8192, T=2048, I=2, H=20, FC(H->1) on last h.
// Round 5: MFMA hybrid. Wave = 16 rows (512 blocks x 64 thr).
//  - j=0..15 pre-acts: one 16x16x32 bf16 MFMA N-tile, split-bf16 for fp32-
//    class accuracy: D = Ahi@B1 + Alo@B1 + Ahi@B3 (B1=W_hi, B3=W_lo).
//    K-slots: k0-19 = h, k20-21 = x0,x1, k22 = 1.0 (bias rides B rows), rest 0.
//  - j=16..19: VALU dot per lane (64 lanes = 16 rows x 4 j) -> tanh perfectly
//    packed (1/lane) instead of paying 20->32 N-padding on the MFMA side.
//  - h relayout D->A through LDS; single wave per block, in-order DS pipe,
//    zero barriers (validated R2/R4). Row stride 36 f32 => <=2-way bank
//    aliasing everywhere (free per m136).

#define T_STEPS 2048
#define B_ROWS  8192
#define NCHUNK  (T_STEPS / 8)

typedef short bf16x8 __attribute__((ext_vector_type(8)));
typedef float f32x4  __attribute__((ext_vector_type(4)));

union PkU { unsigned u[4]; short s[8]; bf16x8 v; };

__device__ __forceinline__ unsigned pk2(float a, float b) {
    // packed bf16(a) | bf16(b)<<16, RNE
    __hip_bfloat162 t = __float22bfloat162_rn(make_float2(a, b));
    union { __hip_bfloat162 h; unsigned u; } c; c.h = t; return c.u;
}

__device__ __forceinline__ float tanh_fast(float a) {
    // tanh(a) = 1 - 2/(exp(2a)+1); exp(2a)=exp2(a*2*log2e). Saturates correctly.
    float e = __builtin_amdgcn_exp2f(a * 2.8853900817779268f);
    float r = __builtin_amdgcn_rcpf(e + 1.0f);
    return fmaf(-2.0f, r, 1.0f);
}

// Zero-instruction compiler ordering fence; HW DS pipe is in-order per wave.
#define LDS_FENCE() asm volatile("" ::: "memory")

__global__ __launch_bounds__(64, 1) void rnn_fused(
    const float* __restrict__ x,      // [B, T, 2]
    const float* __restrict__ W_ih,   // [20, 2]
    const float* __restrict__ W_hh,   // [20, 20]
    const float* __restrict__ b_ih,   // [20]
    const float* __restrict__ b_hh,   // [20]
    const float* __restrict__ fc_w,   // [1, 20]
    const float* __restrict__ fc_b,   // [1]
    float* __restrict__ out)          // [8192] out, then [8192*20] h_state
{
    __shared__ __align__(16) float Ah[16][36];   // 16 rows x 36 f32 (144B stride)

    const int lane = threadIdx.x & 63;
    const int j    = lane & 15;        // MFMA: A-row m / B-col n / D-col j
    const int o    = lane >> 4;        // MFMA k-octet (k = 8o..8o+7)
    const int mV   = lane >> 2;        // VALU/x role: row 0..15
    const int jj   = lane & 3;         // VALU role: j = 16+jj ; x part
    const int rowV = blockIdx.x * 16 + mV;

    // ---- B-fragments (one-time): B[k=8o+t][n=j] ----
    PkU B1, B3;                        // W_hi (+wih_hi,b_hi) / W_lo (+wih_lo,b_lo)
#pragma unroll
    for (int t = 0; t < 8; ++t) {
        const int k = 8 * o + t;
        float w = 0.0f;
        if (k < 20)       w = W_hh[j * 20 + k];
        else if (k == 20) w = W_ih[j * 2 + 0];
        else if (k == 21) w = W_ih[j * 2 + 1];
        else if (k == 22) w = b_ih[j] + b_hh[j];
        const unsigned hb = pk2(w, 0.0f) & 0xFFFFu;
        const float back  = __uint_as_float(hb << 16);
        const float wl    = w - back;
        B1.s[t] = (short)hb;
        B3.s[t] = (short)(pk2(wl, 0.0f) & 0xFFFFu);
    }

    // ---- VALU-side weights for j = 16+jj (one-time) ----
    float wv[20], wx0, wx1, bv;
    {
        const int jv = 16 + jj;
#pragma unroll
        for (int k = 0; k < 20; ++k) wv[k] = W_hh[jv * 20 + k];
        wx0 = W_ih[jv * 2 + 0];
        wx1 = W_ih[jv * 2 + 1];
        bv  = b_ih[jv] + b_hh[jv];
    }

    // ---- init LDS: h=0, slot22=1.0 (bias lane), rest 0 ----
#pragma unroll
    for (int i = 0; i < 9; ++i) {
        const int idx = lane + 64 * i;                 // 9*64 = 576 = 16*36 exactly
        ((float*)Ah)[idx] = ((idx % 36) == 22) ? 1.0f : 0.0f;
    }
    LDS_FENCE();

    // ---- x chunk regs: lane holds steps 8c+2jj, 8c+2jj+1 of row mV ----
    const float4* xq = (const float4*)(x + (size_t)rowV * (T_STEPS * 2));
    float4 q = xq[jj], qn;

    for (int c = 0; c < NCHUNK; ++c) {
        const int cc = (c + 1 < NCHUNK) ? (c + 1) : c;  // clamped dummy prefetch
        qn = xq[4 * cc + jj];

#pragma unroll
        for (int s = 0; s < 8; ++s) {
            // 1. stage x(step) into this row's k20-21 slots (16 active lanes)
            if (jj == (s >> 1)) {
                *(float2*)&Ah[mV][20] = (s & 1) ? make_float2(q.z, q.w)
                                                : make_float2(q.x, q.y);
            }
            LDS_FENCE();
            // 2. reads (h of prev step + x of this step), in-order after writes
            const float4 ra = *(const float4*)&Ah[j][8 * o + 0];
            const float4 rb = *(const float4*)&Ah[j][8 * o + 4];
            const float4 h0 = *(const float4*)&Ah[mV][0];
            const float4 h1 = *(const float4*)&Ah[mV][4];
            const float4 h2 = *(const float4*)&Ah[mV][8];
            const float4 h3 = *(const float4*)&Ah[mV][12];
            const float4 h4 = *(const float4*)&Ah[mV][16];
            const float2 xv = *(const float2*)&Ah[mV][20];
            LDS_FENCE();
            // 3. split f32 -> (hi, lo) bf16 fragments
            PkU Ahi, Alo;
            {
                const float f[8] = {ra.x, ra.y, ra.z, ra.w, rb.x, rb.y, rb.z, rb.w};
#pragma unroll
                for (int p = 0; p < 4; ++p) {
                    const unsigned hp = pk2(f[2 * p], f[2 * p + 1]);
                    Ahi.u[p] = hp;
                    const float b0 = __uint_as_float(hp << 16);
                    const float b1 = __uint_as_float(hp & 0xFFFF0000u);
                    Alo.u[p] = pk2(f[2 * p] - b0, f[2 * p + 1] - b1);
                }
            }
            // 4. MFMA (j0-15) + VALU dot (j16-19)
            f32x4 d = {0.0f, 0.0f, 0.0f, 0.0f};
            d = __builtin_amdgcn_mfma_f32_16x16x32_bf16(Ahi.v, B1.v, d, 0, 0, 0);
            d = __builtin_amdgcn_mfma_f32_16x16x32_bf16(Alo.v, B1.v, d, 0, 0, 0);
            d = __builtin_amdgcn_mfma_f32_16x16x32_bf16(Ahi.v, B3.v, d, 0, 0, 0);

            float av = fmaf(xv.y, wx1, fmaf(xv.x, wx0, bv));
            av = fmaf(h0.x, wv[0],  av); av = fmaf(h0.y, wv[1],  av);
            av = fmaf(h0.z, wv[2],  av); av = fmaf(h0.w, wv[3],  av);
            av = fmaf(h1.x, wv[4],  av); av = fmaf(h1.y, wv[5],  av);
            av = fmaf(h1.z, wv[6],  av); av = fmaf(h1.w, wv[7],  av);
            av = fmaf(h2.x, wv[8],  av); av = fmaf(h2.y, wv[9],  av);
            av = fmaf(h2.z, wv[10], av); av = fmaf(h2.w, wv[11], av);
            av = fmaf(h3.x, wv[12], av); av = fmaf(h3.y, wv[13], av);
            av = fmaf(h3.z, wv[14], av); av = fmaf(h3.w, wv[15], av);
            av = fmaf(h4.x, wv[16], av); av = fmaf(h4.y, wv[17], av);
            av = fmaf(h4.z, wv[18], av); av = fmaf(h4.w, wv[19], av);

            // 5. tanh (4 MFMA outputs + 1 packed VALU output per lane)
            const float t0 = tanh_fast(d[0]);
            const float t1 = tanh_fast(d[1]);
            const float t2 = tanh_fast(d[2]);
            const float t3 = tanh_fast(d[3]);
            const float tv = tanh_fast(av);

            // 6. write h(step): D rows 4o+r col j ; VALU slot 16+jj of row mV
            Ah[4 * o + 0][j] = t0;
            Ah[4 * o + 1][j] = t1;
            Ah[4 * o + 2][j] = t2;
            Ah[4 * o + 3][j] = t3;
            Ah[mV][16 + jj]  = tv;
            LDS_FENCE();
        }
        q = qn;
    }

    // ---- epilogue: Ah rows hold h_T (slots 0-19) ----
    LDS_FENCE();
    float hs0 = Ah[mV][5 * jj + 0];
    float hs1 = Ah[mV][5 * jj + 1];
    float hs2 = Ah[mV][5 * jj + 2];
    float hs3 = Ah[mV][5 * jj + 3];
    float hs4 = Ah[mV][5 * jj + 4];
    {
        float* hs = out + B_ROWS + (size_t)rowV * 20 + 5 * jj;
        hs[0] = hs0; hs[1] = hs1; hs[2] = hs2; hs[3] = hs3; hs[4] = hs4;
    }
    {
        const float* fw = fc_w + 5 * jj;
        float p = hs0 * fw[0];
        p = fmaf(hs1, fw[1], p);
        p = fmaf(hs2, fw[2], p);
        p = fmaf(hs3, fw[3], p);
        p = fmaf(hs4, fw[4], p);
        p += __shfl_xor(p, 1, 64);
        p += __shfl_xor(p, 2, 64);
        if (jj == 0) out[rowV] = p + fc_b[0];
    }
}

extern "C" void kernel_launch(void* const* d_in, const int* in_sizes, int n_in,
                              void* d_out, int out_size, void* d_ws, size_t ws_size,
                              hipStream_t stream) {
    const float* x    = (const float*)d_in[0];
    const float* W_ih = (const float*)d_in[1];
    const float* W_hh = (const float*)d_in[2];
    const float* b_ih = (const float*)d_in[3];
    const float* b_hh = (const float*)d_in[4];
    const float* fc_w = (const float*)d_in[5];
    const float* fc_b = (const float*)d_in[6];
    float* out = (float*)d_out;

    // 512 blocks x 64 threads: one wave per block, 16 rows per wave
    rnn_fused<<<512, 64, 0, stream>>>(x, W_ih, W_hh, b_ih, b_hh, fc_w, fc_b, out);
}

// Round 7
// 570.546 us; speedup vs baseline: 1.4194x; 1.4194x over previous
//
#include <hip/hip_runtime.h>

// Tanh-RNN: B=8192, T=2048, I=2, H=20, FC(H->1) on last h.
// Round 7: identical to R6 except the dpp_xor4 direction fix.
// Scheme: R2's j-split (8 lanes/row, 3 j/lane, 8 rows/wave, 1024 waves =
// 1/SIMD) with the h-allgather done entirely in VALU DPP ops — NO LDS, no
// shfl, no barriers. Butterfly: xor4 (masked row_shl/shr:4), then xor1
// (quad_perm 0xB1), then xor2 (quad_perm 0x4E): 24 full-rate instrs, ~4 cyc
// latency/stage, vs the ~140-cyc LDS write->read turnaround of R2/R4/R5.
// DPP semantics (from AMD's canonical row_shr scan idiom):
//   row_shr:N -> dst lane i reads lane i-N ; row_shl:N -> reads lane i+N.
// So lanes 0-3/8-11 (need L+4) use row_shl:4, lanes 4-7/12-15 use row_shr:4.
// R6 had these swapped -> misrouted h -> absmax 0.63. Fixed here.

#define T_STEPS 2048
#define B_ROWS  8192
#define NCHUNK  (T_STEPS / 8)

__device__ __forceinline__ float tanh_fast(float a) {
    // tanh(a) = 1 - 2/(exp(2a)+1); exp(2a)=exp2(a*2*log2e). Saturates correctly.
    float e = __builtin_amdgcn_exp2f(a * 2.8853900817779268f);
    float r = __builtin_amdgcn_rcpf(e + 1.0f);
    return fmaf(-2.0f, r, 1.0f);
}

__device__ __forceinline__ float2 fma2(float2 a, float2 b, float2 c) {
    return make_float2(fmaf(a.x, b.x, c.x), fmaf(a.y, b.y, c.y));
}

// ---- DPP cross-lane (within a 16-lane DPP row; octet = aligned half-row) ----
#define XOR1_CTRL 0xB1   // quad_perm(1,0,3,2): lane^1
#define XOR2_CTRL 0x4E   // quad_perm(2,3,0,1): lane^2

template <int CTRL>
__device__ __forceinline__ float dpp_full(float v) {
    return __int_as_float(__builtin_amdgcn_update_dpp(
        0, __float_as_int(v), CTRL, 0xF, 0xF, true));
}

// lane^4 within each 8-lane octet (16-lane DPP row holds 2 octets):
//   lanes 0-3, 8-11  (banks 0,2): need src L+4 -> row_shl:4 (0x104)
//   lanes 4-7, 12-15 (banks 1,3): need src L-4 -> row_shr:4 (0x114)
__device__ __forceinline__ float dpp_xor4(float v) {
    int t = __builtin_amdgcn_update_dpp(__float_as_int(v), __float_as_int(v),
                                        0x104 /*row_shl:4*/, 0xF, 0x5, false);
    t = __builtin_amdgcn_update_dpp(t, __float_as_int(v),
                                    0x114 /*row_shr:4*/, 0xF, 0xA, false);
    return __int_as_float(t);
}

__global__ __launch_bounds__(64, 1) void rnn_fused(
    const float* __restrict__ x,      // [B, T, 2]
    const float* __restrict__ W_ih,   // [20, 2]
    const float* __restrict__ W_hh,   // [20, 20]
    const float* __restrict__ b_ih,   // [20]
    const float* __restrict__ b_hh,   // [20]
    const float* __restrict__ fc_w,   // [1, 20]
    const float* __restrict__ fc_b,   // [1]
    float* __restrict__ out)          // [8192] out, then [8192*20] h_state
{
    const int lane = threadIdx.x & 63;
    const int g    = lane & 7;        // owns j = 3g..3g+2
    const int r    = lane >> 3;       // row within wave
    const int row  = blockIdx.x * 8 + r;

    // Butterfly slot order: after stages (xor4, xor1, xor2) below, the lane's
    // 24-slot h vector holds triplets of g' = g ^ M[slot/3]:
    //   M = {0,4,1,5,2,6,3,7}
    // Weights are loaded matching this per-lane order (k >= 20 or j >= 20 -> 0).
    const int M[8] = {0, 4, 1, 5, 2, 6, 3, 7};

    float2 W2[3][12];                 // pair p covers slots 2p, 2p+1 of hg[]
    float  wi0[3], wi1[3], bsum[3], fcw[3];
#pragma unroll
    for (int jj = 0; jj < 3; ++jj) {
        const int j = 3 * g + jj;
        const bool v = (j < 20);
#pragma unroll
        for (int p = 0; p < 12; ++p) {
            float wv[2];
#pragma unroll
            for (int h = 0; h < 2; ++h) {
                const int slot = 2 * p + h;
                const int k = 3 * (g ^ M[slot / 3]) + (slot % 3);
                wv[h] = (v && k < 20) ? W_hh[j * 20 + k] : 0.0f;
            }
            W2[jj][p] = make_float2(wv[0], wv[1]);
        }
        wi0[jj]  = v ? W_ih[j * 2 + 0] : 0.0f;
        wi1[jj]  = v ? W_ih[j * 2 + 1] : 0.0f;
        bsum[jj] = v ? (b_ih[j] + b_hh[j]) : 0.0f;
        fcw[jj]  = v ? fc_w[j] : 0.0f;
    }

    float hg[24];                     // gathered h in butterfly slot order
#pragma unroll
    for (int i = 0; i < 24; ++i) hg[i] = 0.0f;
    float hn0 = 0.0f, hn1 = 0.0f, hn2 = 0.0f;

    auto step = [&](float x0, float x1) {
        float2 c0 = make_float2(fmaf(x0, wi0[0], bsum[0]), x1 * wi1[0]);
        float2 c1 = make_float2(fmaf(x0, wi0[1], bsum[1]), x1 * wi1[1]);
        float2 c2 = make_float2(fmaf(x0, wi0[2], bsum[2]), x1 * wi1[2]);
#pragma unroll
        for (int p = 0; p < 12; ++p) {
            const float2 hp = make_float2(hg[2 * p], hg[2 * p + 1]);
            c0 = fma2(hp, W2[0][p], c0);
            c1 = fma2(hp, W2[1][p], c1);
            c2 = fma2(hp, W2[2][p], c2);
        }
        hn0 = tanh_fast(c0.x + c0.y);
        hn1 = tanh_fast(c1.x + c1.y);
        hn2 = tanh_fast(c2.x + c2.y);
        // ---- DPP butterfly allgather (24 VALU instrs, no LDS) ----
        hg[0] = hn0; hg[1] = hn1; hg[2] = hn2;
        hg[3] = dpp_xor4(hg[0]);
        hg[4] = dpp_xor4(hg[1]);
        hg[5] = dpp_xor4(hg[2]);
#pragma unroll
        for (int i = 0; i < 6; ++i)  hg[6 + i]  = dpp_full<XOR1_CTRL>(hg[i]);
#pragma unroll
        for (int i = 0; i < 12; ++i) hg[12 + i] = dpp_full<XOR2_CTRL>(hg[i]);
    };

    // x: per 8-step chunk, 4 float4 per lane (octet shares the cacheline, L1
    // broadcast); double-buffered one chunk ahead.
    const float4* xq = (const float4*)(x + (size_t)row * (T_STEPS * 2));
    float4 q[4], qn[4];
#pragma unroll
    for (int i = 0; i < 4; ++i) q[i] = xq[i];

    for (int c = 0; c < NCHUNK; ++c) {
        const int cn = (c + 1 < NCHUNK) ? (c + 1) : c;   // clamped dummy prefetch
#pragma unroll
        for (int i = 0; i < 4; ++i) qn[i] = xq[4 * cn + i];

        step(q[0].x, q[0].y); step(q[0].z, q[0].w);
        step(q[1].x, q[1].y); step(q[1].z, q[1].w);
        step(q[2].x, q[2].y); step(q[2].z, q[2].w);
        step(q[3].x, q[3].y); step(q[3].z, q[3].w);

#pragma unroll
        for (int i = 0; i < 4; ++i) q[i] = qn[i];
    }

    // ---- epilogue ----
    // h_state: [1, B, H] flat at offset B_ROWS; lane stores its own 3 j's
    {
        const int j0 = 3 * g;
        float* hs = out + B_ROWS + (size_t)row * 20;
        if (j0 + 0 < 20) hs[j0 + 0] = hn0;
        if (j0 + 1 < 20) hs[j0 + 1] = hn1;
        if (j0 + 2 < 20) hs[j0 + 2] = hn2;
    }
    // FC: per-lane partial over own j's, octet tree-reduce via DPP butterfly
    {
        float p = hn0 * fcw[0];
        p = fmaf(hn1, fcw[1], p);
        p = fmaf(hn2, fcw[2], p);
        p += dpp_full<XOR1_CTRL>(p);
        p += dpp_full<XOR2_CTRL>(p);
        p += dpp_xor4(p);
        if (g == 0) out[row] = p + fc_b[0];
    }
}

extern "C" void kernel_launch(void* const* d_in, const int* in_sizes, int n_in,
                              void* d_out, int out_size, void* d_ws, size_t ws_size,
                              hipStream_t stream) {
    const float* x    = (const float*)d_in[0];
    const float* W_ih = (const float*)d_in[1];
    const float* W_hh = (const float*)d_in[2];
    const float* b_ih = (const float*)d_in[3];
    const float* b_hh = (const float*)d_in[4];
    const float* fc_w = (const float*)d_in[5];
    const float* fc_b = (const float*)d_in[6];
    float* out = (float*)d_out;

    // 1024 blocks x 64 threads: 1 wave/block, 8 rows/wave -> 1 wave/SIMD
    rnn_fused<<<1024, 64, 0, stream>>>(x, W_ih, W_hh, b_ih, b_hh, fc_w, fc_b, out);
}